// Round 1
// baseline (1487.171 us; speedup 1.0000x reference)
//
#include <hip/hip_runtime.h>
#include <math.h>

#define H 512
#define B 32
#define S 1024
#define V 50000

// ---- workspace layout (float offsets) ----
#define ZT_OFF   0         // zT [1536][32]
#define GT_OFF   49152     // gatesT [2048][32]
#define CT_OFF   114688    // cT [512][32]
#define Q_OFF    131072    // q [32][512]
#define YT_OFF   147456    // yT [1024][32]
#define SC_OFF   180224    // scores [32][1024]
#define PAR_OFF  212992    // partial ctx [32][32][512]
#define LSEP_OFF 737280    // lse partials [32][16][2]

// ---- d_out layout (float offsets) ----
#define DO_OUT   0         // [B][V] log-softmax
#define DO_CTX   1600000   // [B][H]
#define DO_H     1616384   // [B][H]
#define DO_C     1632768   // [B][H]
#define DO_ATTN  1649152   // [B][S]

// ============ k_prep: embedding gather -> zT rows, q = we @ W_a ============
__global__ void k_prep(const int* __restrict__ wi, const float* __restrict__ lc,
                       const float* __restrict__ h0, const float* __restrict__ emb,
                       const float* __restrict__ Wa,
                       float* __restrict__ zT, float* __restrict__ q) {
    int t = blockIdx.x * 256 + threadIdx.x;      // 0..16383
    int b = t >> 9, h = t & (H - 1);
    const float* er = emb + (long long)wi[b] * H;
    float e = er[h];
    zT[h * 32 + b]           = e;                // x part 1 (output)
    zT[(H + h) * 32 + b]     = lc[b * H + h];    // x part 2 (last_context)
    zT[(2 * H + h) * 32 + b] = h0[b * H + h];    // hidden
    float acc = 0.f;
    #pragma unroll 8
    for (int k = 0; k < H; ++k) acc += er[k] * Wa[k * H + h];
    q[b * H + h] = acc;
}

// ============ k_gates: one block per gate row r; gatesT[r][b] ============
__global__ void k_gates(const float* __restrict__ zT, const float* __restrict__ Wih,
                        const float* __restrict__ Whh, const float* __restrict__ bih,
                        const float* __restrict__ bhh, float* __restrict__ gT) {
    __shared__ float red[8][32];
    int r = blockIdx.x;                 // 0..2047
    int t = threadIdx.x;
    int kg = t >> 5, b = t & 31;
    int k0 = kg * 192;
    const float* wih_r = Wih + (long long)r * 1024;
    const float* whh_r = Whh + (long long)r * 512;
    float acc = 0.f;
    int n_ih = (k0 < 1024) ? ((1024 - k0 < 192) ? (1024 - k0) : 192) : 0;
    #pragma unroll 4
    for (int j = 0; j < n_ih; ++j) {
        int k = k0 + j;
        acc += wih_r[k] * zT[k * 32 + b];
    }
    #pragma unroll 4
    for (int j = n_ih; j < 192; ++j) {
        int k = k0 + j;
        acc += whh_r[k - 1024] * zT[k * 32 + b];
    }
    red[kg][b] = acc;
    __syncthreads();
    if (t < 32) {
        float s = bih[r] + bhh[r];
        #pragma unroll
        for (int kk = 0; kk < 8; ++kk) s += red[kk][t];
        gT[r * 32 + t] = s;
    }
}

// ============ k_point: LSTM pointwise. layer 0 feeds zT, layer 1 finalizes ====
__global__ void k_point(const float* __restrict__ gT, const float* __restrict__ cprev,
                        int layer, float* __restrict__ zT, float* __restrict__ cT,
                        float* __restrict__ yT, float* __restrict__ hOut,
                        float* __restrict__ cOut) {
    int t = blockIdx.x * 256 + threadIdx.x;      // 0..16383
    int b = t & 31, hi = t >> 5;
    float gi = gT[hi * 32 + b];
    float gf = gT[(512 + hi) * 32 + b];
    float gg = gT[(1024 + hi) * 32 + b];
    float go = gT[(1536 + hi) * 32 + b];
    float si = 1.f / (1.f + expf(-gi));
    float sf = 1.f / (1.f + expf(-gf));
    float so = 1.f / (1.f + expf(-go));
    float c = (layer == 0) ? cprev[b * H + hi] : cprev[hi * 32 + b];
    float cn = sf * c + si * tanhf(gg);
    float hn = so * tanhf(cn);
    if (layer == 0) {
        zT[hi * 32 + b] = hn;                 // next x part 1
        zT[(2 * H + hi) * 32 + b] = hn;       // next hidden
        cT[hi * 32 + b] = cn;
    } else {
        yT[hi * 32 + b] = hn;                 // y = [h2, ctx], first half
        hOut[b * H + hi] = hn;
        cOut[b * H + hi] = cn;
    }
}

// ============ k_scores: one wave per (b,s) dot(q_b, enc_sb) ============
__global__ void k_scores(const float* __restrict__ q, const float* __restrict__ enc,
                         float* __restrict__ sc) {
    int w = (blockIdx.x * 256 + threadIdx.x) >> 6;   // 0..32767
    int lane = threadIdx.x & 63;
    int b = w >> 10, s = w & 1023;
    const float4* e4 = (const float4*)(enc + ((long long)(s * 32 + b)) * H);
    const float4* q4 = (const float4*)(q + b * H);
    float4 a0 = e4[lane * 2], a1 = e4[lane * 2 + 1];
    float4 b0 = q4[lane * 2], b1 = q4[lane * 2 + 1];
    float v = a0.x * b0.x + a0.y * b0.y + a0.z * b0.z + a0.w * b0.w
            + a1.x * b1.x + a1.y * b1.y + a1.z * b1.z + a1.w * b1.w;
    #pragma unroll
    for (int off = 32; off > 0; off >>= 1) v += __shfl_xor(v, off);
    if (lane == 0) sc[b * S + s] = v;
}

// ============ k_softmax: block per b over S=1024 ============
__global__ void k_softmax(const float* __restrict__ sc, float* __restrict__ attn) {
    __shared__ float red[8];
    int b = blockIdx.x, t = threadIdx.x;
    float v[4];
    float m = -1e30f;
    #pragma unroll
    for (int i = 0; i < 4; ++i) {
        v[i] = sc[b * S + i * 256 + t];
        m = fmaxf(m, v[i]);
    }
    #pragma unroll
    for (int off = 32; off > 0; off >>= 1) m = fmaxf(m, __shfl_xor(m, off));
    if ((t & 63) == 0) red[t >> 6] = m;
    __syncthreads();
    m = fmaxf(fmaxf(red[0], red[1]), fmaxf(red[2], red[3]));
    float e[4], l = 0.f;
    #pragma unroll
    for (int i = 0; i < 4; ++i) { e[i] = expf(v[i] - m); l += e[i]; }
    #pragma unroll
    for (int off = 32; off > 0; off >>= 1) l += __shfl_xor(l, off);
    if ((t & 63) == 0) red[4 + (t >> 6)] = l;
    __syncthreads();
    l = red[4] + red[5] + red[6] + red[7];
    float inv = 1.f / l;
    #pragma unroll
    for (int i = 0; i < 4; ++i) attn[b * S + i * 256 + t] = e[i] * inv;
}

// ============ k_ctxp: partial context over s-chunks ============
__global__ void k_ctxp(const float* __restrict__ attn, const float* __restrict__ enc,
                       float* __restrict__ par) {
    int b = blockIdx.x >> 5, ch = blockIdx.x & 31;
    int t = threadIdx.x;
    float a0 = 0.f, a1 = 0.f;
    for (int si = 0; si < 32; ++si) {
        int s = ch * 32 + si;
        float a = attn[b * S + s];
        const float* eb = enc + ((long long)(s * 32 + b)) * H;
        a0 += a * eb[t];
        a1 += a * eb[256 + t];
    }
    float* p = par + (long long)(ch * 32 + b) * H;
    p[t] = a0;
    p[256 + t] = a1;
}

// ============ k_ctxr: reduce 32 chunks -> context ============
__global__ void k_ctxr(const float* __restrict__ par, float* __restrict__ ctxOut,
                       float* __restrict__ yT) {
    int idx = blockIdx.x * 256 + threadIdx.x;    // 0..16383
    int b = idx >> 9, h = idx & (H - 1);
    float s = 0.f;
    #pragma unroll 4
    for (int c = 0; c < 32; ++c) s += par[c * 16384 + b * H + h];
    ctxOut[b * H + h] = s;
    yT[(H + h) * 32 + b] = s;                    // y second half
}

// ============ k_gemm: logits[b][v] = y_b . Wout_v + bout_v ============
// 64 v-rows per block; 256 thr = 8 kg x 4 bg x 8 vg; thread tile 8v x 8b.
#define RED_WRITE(reg) { float* rr = WT + (reg) * 2112;                       \
    _Pragma("unroll") for (int d = 0; d < 8; ++d) { int vl = vg + 8 * d;      \
    _Pragma("unroll") for (int e = 0; e < 8; ++e)                             \
        rr[vl * 33 + bg * 8 + e] = acc[d][e]; } }
#define RED_ADD(reg) { float* rr = WT + (reg) * 2112;                         \
    _Pragma("unroll") for (int d = 0; d < 8; ++d) { int vl = vg + 8 * d;      \
    _Pragma("unroll") for (int e = 0; e < 8; ++e)                             \
        acc[d][e] += rr[vl * 33 + bg * 8 + e]; } }

__global__ __launch_bounds__(256, 3)
void k_gemm(const float* __restrict__ Wout, const float* __restrict__ yTg,
            const float* __restrict__ bout, float* __restrict__ out) {
    __shared__ float WT[64 * 132];   // W tile [64 v][128 k], pad 132
    __shared__ float YS[128 * 32];   // yT tile [128 k][32 b]
    int tid = threadIdx.x;
    int v0 = blockIdx.x * 64;
    int kg = tid >> 5;
    int bg = (tid >> 3) & 3;
    int vg = tid & 7;
    float acc[8][8];
    #pragma unroll
    for (int d = 0; d < 8; ++d)
        #pragma unroll
        for (int e = 0; e < 8; ++e) acc[d][e] = 0.f;

    for (int kc = 0; kc < 1024; kc += 128) {
        // stage W tile (coalesced float4 rows), guard v >= V with zeros
        #pragma unroll
        for (int i = 0; i < 8; ++i) {
            int f = tid + i * 256;
            int v = f >> 5, j = f & 31;
            int gv = v0 + v;
            float4 w4 = make_float4(0.f, 0.f, 0.f, 0.f);
            if (gv < V) w4 = *(const float4*)(Wout + (long long)gv * 1024 + kc + j * 4);
            *(float4*)(WT + v * 132 + j * 4) = w4;
        }
        // stage y tile (contiguous)
        #pragma unroll
        for (int i = 0; i < 4; ++i) {
            int f = tid + i * 256;
            float4 y4 = *(const float4*)(yTg + kc * 32 + f * 4);
            *(float4*)(YS + f * 4) = y4;
        }
        __syncthreads();
        // compute: this thread's k range = [kg*16, kg*16+16) of chunk, in 4-groups
        #pragma unroll
        for (int g = 0; g < 4; ++g) {
            int k0 = kg * 16 + g * 4;
            float4 ya[4], yb[4];
            #pragma unroll
            for (int kk = 0; kk < 4; ++kk) {
                ya[kk] = *(const float4*)(YS + (k0 + kk) * 32 + bg * 8);
                yb[kk] = *(const float4*)(YS + (k0 + kk) * 32 + bg * 8 + 4);
            }
            #pragma unroll
            for (int d = 0; d < 8; ++d) {
                float4 w4 = *(const float4*)(WT + (vg + 8 * d) * 132 + k0);
                acc[d][0] += w4.x * ya[0].x + w4.y * ya[1].x + w4.z * ya[2].x + w4.w * ya[3].x;
                acc[d][1] += w4.x * ya[0].y + w4.y * ya[1].y + w4.z * ya[2].y + w4.w * ya[3].y;
                acc[d][2] += w4.x * ya[0].z + w4.y * ya[1].z + w4.z * ya[2].z + w4.w * ya[3].z;
                acc[d][3] += w4.x * ya[0].w + w4.y * ya[1].w + w4.z * ya[2].w + w4.w * ya[3].w;
                acc[d][4] += w4.x * yb[0].x + w4.y * yb[1].x + w4.z * yb[2].x + w4.w * yb[3].x;
                acc[d][5] += w4.x * yb[0].y + w4.y * yb[1].y + w4.z * yb[2].y + w4.w * yb[3].y;
                acc[d][6] += w4.x * yb[0].z + w4.y * yb[1].z + w4.z * yb[2].z + w4.w * yb[3].z;
                acc[d][7] += w4.x * yb[0].w + w4.y * yb[1].w + w4.z * yb[2].w + w4.w * yb[3].w;
            }
        }
        __syncthreads();
    }

    // tree-reduce the 8 kg partials in LDS (WT reused; region stride 2112)
    if (kg >= 4) RED_WRITE(kg - 4);
    __syncthreads();
    if (kg < 4) RED_ADD(kg);
    __syncthreads();
    if (kg >= 2 && kg < 4) RED_WRITE(kg - 2);
    __syncthreads();
    if (kg < 2) RED_ADD(kg);
    __syncthreads();
    if (kg == 1) RED_WRITE(0);
    __syncthreads();
    if (kg == 0) {
        RED_ADD(0);
        #pragma unroll
        for (int d = 0; d < 8; ++d) {
            int gv = v0 + vg + 8 * d;
            if (gv < V) {
                float bo = bout[gv];
                #pragma unroll
                for (int e = 0; e < 8; ++e)
                    out[(long long)(bg * 8 + e) * V + gv] = acc[d][e] + bo;
            }
        }
    }
}

// ============ k_lsep: per (b, chunk) online max/sumexp over logits ============
__global__ void k_lsep(const float* __restrict__ out, float* __restrict__ lsep) {
    __shared__ float rm[4], rl[4];
    int b = blockIdx.x >> 4, ch = blockIdx.x & 15;
    int t = threadIdx.x;
    int start = ch * 3125, end = start + 3125;
    float m = -1e30f, l = 0.f;
    for (int v = start + t; v < end; v += 256) {
        float x = out[(long long)b * V + v];
        float nm = fmaxf(m, x);
        l = l * expf(m - nm) + expf(x - nm);
        m = nm;
    }
    #pragma unroll
    for (int off = 32; off > 0; off >>= 1) {
        float m2 = __shfl_xor(m, off);
        float l2 = __shfl_xor(l, off);
        float nm = fmaxf(m, m2);
        l = l * expf(m - nm) + l2 * expf(m2 - nm);
        m = nm;
    }
    if ((t & 63) == 0) { rm[t >> 6] = m; rl[t >> 6] = l; }
    __syncthreads();
    if (t == 0) {
        m = rm[0]; l = rl[0];
        for (int i = 1; i < 4; ++i) {
            float nm = fmaxf(m, rm[i]);
            l = l * expf(m - nm) + rl[i] * expf(rm[i] - nm);
            m = nm;
        }
        lsep[(b * 16 + ch) * 2] = m;
        lsep[(b * 16 + ch) * 2 + 1] = l;
    }
}

// ============ k_final: merge lse chunks, out = logits - lse[b] (in place) ====
__global__ void k_final(const float* __restrict__ lsep, float* __restrict__ out) {
    __shared__ float lse[32];
    int t = threadIdx.x;
    if (t < 32) {
        float m = lsep[t * 32], l = lsep[t * 32 + 1];
        for (int i = 1; i < 16; ++i) {
            float m2 = lsep[t * 32 + i * 2], l2 = lsep[t * 32 + i * 2 + 1];
            float nm = fmaxf(m, m2);
            l = l * expf(m - nm) + l2 * expf(m2 - nm);
            m = nm;
        }
        lse[t] = m + logf(l);
    }
    __syncthreads();
    int idx0 = blockIdx.x * 2048 + t;
    #pragma unroll
    for (int i = 0; i < 8; ++i) {
        int idx = idx0 + i * 256;
        if (idx < B * V) {
            int b = idx / V;
            out[idx] -= lse[b];
        }
    }
}

extern "C" void kernel_launch(void* const* d_in, const int* in_sizes, int n_in,
                              void* d_out, int out_size, void* d_ws, size_t ws_size,
                              hipStream_t stream) {
    const int*   wi   = (const int*)d_in[0];
    const float* lc   = (const float*)d_in[1];
    const float* h0   = (const float*)d_in[2];
    const float* c0   = (const float*)d_in[3];
    const float* enc  = (const float*)d_in[4];
    const float* emb  = (const float*)d_in[5];
    const float* Wih  = (const float*)d_in[6];
    const float* Whh  = (const float*)d_in[7];
    const float* bih  = (const float*)d_in[8];
    const float* bhh  = (const float*)d_in[9];
    const float* Wa   = (const float*)d_in[10];
    // d_in[11] = b_a: provably cancels in softmax -> unused
    const float* Wout = (const float*)d_in[12];
    const float* bout = (const float*)d_in[13];
    float* out = (float*)d_out;
    float* ws  = (float*)d_ws;

    float* zT   = ws + ZT_OFF;
    float* gT   = ws + GT_OFF;
    float* cT   = ws + CT_OFF;
    float* q    = ws + Q_OFF;
    float* yT   = ws + YT_OFF;
    float* sc   = ws + SC_OFF;
    float* par  = ws + PAR_OFF;
    float* lsep = ws + LSEP_OFF;

    k_prep<<<64, 256, 0, stream>>>(wi, lc, h0, emb, Wa, zT, q);
    k_gates<<<2048, 256, 0, stream>>>(zT, Wih, Whh, bih, bhh, gT);
    k_point<<<64, 256, 0, stream>>>(gT, c0, 0, zT, cT, yT, out + DO_H, out + DO_C);
    k_gates<<<2048, 256, 0, stream>>>(zT, Wih, Whh, bih, bhh, gT);
    k_point<<<64, 256, 0, stream>>>(gT, cT, 1, zT, cT, yT, out + DO_H, out + DO_C);
    k_scores<<<8192, 256, 0, stream>>>(q, enc, sc);
    k_softmax<<<32, 256, 0, stream>>>(sc, out + DO_ATTN);
    k_ctxp<<<1024, 256, 0, stream>>>(out + DO_ATTN, enc, par);
    k_ctxr<<<64, 256, 0, stream>>>(par, out + DO_CTX, yT);
    k_gemm<<<(V + 63) / 64, 256, 0, stream>>>(Wout, yT, bout, out + DO_OUT);
    k_lsep<<<512, 256, 0, stream>>>(out + DO_OUT, lsep);
    k_final<<<782, 256, 0, stream>>>(lsep, out + DO_OUT);
}

// Round 2
// 813.896 us; speedup vs baseline: 1.8272x; 1.8272x over previous
//
#include <hip/hip_runtime.h>
#include <math.h>

#define H 512
#define B 32
#define S 1024
#define V 50000

// ---- workspace layout (float offsets) ----
#define ZT_OFF   0         // zT [1536][32]
#define GT_OFF   49152     // gatesT [2048][32]
#define CT_OFF   114688    // cT [512][32]
#define Q_OFF    131072    // q [32][512]
#define YT_OFF   147456    // yT [1024][32]
#define SC_OFF   180224    // scores [32][1024]
#define PAR_OFF  212992    // partial ctx [32][32][512]
#define LSEP_OFF 737280    // lse partials [32][16][2]

// ---- d_out layout (float offsets) ----
#define DO_OUT   0         // [B][V] log-softmax
#define DO_CTX   1600000   // [B][H]
#define DO_H     1616384   // [B][H]
#define DO_C     1632768   // [B][H]
#define DO_ATTN  1649152   // [B][S]

// ============ k_prep: zT fill + q = we @ W_a (4-way k-split) ============
// grid 256: b = blk>>3, hq = blk&7 (64 h per block); 256 thr = 4 kg x 64 hl
__global__ void k_prep(const int* __restrict__ wi, const float* __restrict__ lc,
                       const float* __restrict__ h0, const float* __restrict__ emb,
                       const float* __restrict__ Wa,
                       float* __restrict__ zT, float* __restrict__ q) {
    __shared__ float ech[512];
    __shared__ float red[4][64];
    int t = threadIdx.x;
    int b = blockIdx.x >> 3, hq = blockIdx.x & 7;
    int hl = t & 63, kg = t >> 6;
    int h = hq * 64 + hl;
    const float* er = emb + (long long)wi[b] * H;
    ech[t] = er[t];
    ech[256 + t] = er[256 + t];
    __syncthreads();
    if (kg == 0)      zT[h * 32 + b]           = ech[h];          // x part 1
    else if (kg == 1) zT[(H + h) * 32 + b]     = lc[b * H + h];   // x part 2
    else if (kg == 2) zT[(2 * H + h) * 32 + b] = h0[b * H + h];   // hidden
    float acc = 0.f;
    #pragma unroll 8
    for (int j = 0; j < 128; ++j) {
        int k = kg * 128 + j;
        acc += ech[k] * Wa[k * H + h];
    }
    red[kg][hl] = acc;
    __syncthreads();
    if (kg == 0) q[b * H + h] = red[0][hl] + red[1][hl] + red[2][hl] + red[3][hl];
}

// ============ k_gates: one block per gate row r; gatesT[r][b] ============
__global__ void k_gates(const float* __restrict__ zT, const float* __restrict__ Wih,
                        const float* __restrict__ Whh, const float* __restrict__ bih,
                        const float* __restrict__ bhh, float* __restrict__ gT) {
    __shared__ float red[8][32];
    int r = blockIdx.x;                 // 0..2047
    int t = threadIdx.x;
    int kg = t >> 5, b = t & 31;
    int k0 = kg * 192;
    const float* wih_r = Wih + (long long)r * 1024;
    const float* whh_r = Whh + (long long)r * 512;
    float acc = 0.f;
    int n_ih = (k0 < 1024) ? ((1024 - k0 < 192) ? (1024 - k0) : 192) : 0;
    #pragma unroll 4
    for (int j = 0; j < n_ih; ++j) {
        int k = k0 + j;
        acc += wih_r[k] * zT[k * 32 + b];
    }
    #pragma unroll 4
    for (int j = n_ih; j < 192; ++j) {
        int k = k0 + j;
        acc += whh_r[k - 1024] * zT[k * 32 + b];
    }
    red[kg][b] = acc;
    __syncthreads();
    if (t < 32) {
        float s = bih[r] + bhh[r];
        #pragma unroll
        for (int kk = 0; kk < 8; ++kk) s += red[kk][t];
        gT[r * 32 + t] = s;
    }
}

// ============ k_point: LSTM pointwise. layer 0 feeds zT, layer 1 finalizes ====
__global__ void k_point(const float* __restrict__ gT, const float* __restrict__ cprev,
                        int layer, float* __restrict__ zT, float* __restrict__ cT,
                        float* __restrict__ yT, float* __restrict__ hOut,
                        float* __restrict__ cOut) {
    int t = blockIdx.x * 256 + threadIdx.x;      // 0..16383
    int b = t & 31, hi = t >> 5;
    float gi = gT[hi * 32 + b];
    float gf = gT[(512 + hi) * 32 + b];
    float gg = gT[(1024 + hi) * 32 + b];
    float go = gT[(1536 + hi) * 32 + b];
    float si = 1.f / (1.f + expf(-gi));
    float sf = 1.f / (1.f + expf(-gf));
    float so = 1.f / (1.f + expf(-go));
    float c = (layer == 0) ? cprev[b * H + hi] : cprev[hi * 32 + b];
    float cn = sf * c + si * tanhf(gg);
    float hn = so * tanhf(cn);
    if (layer == 0) {
        zT[hi * 32 + b] = hn;                 // next x part 1
        zT[(2 * H + hi) * 32 + b] = hn;       // next hidden
        cT[hi * 32 + b] = cn;
    } else {
        yT[hi * 32 + b] = hn;                 // y = [h2, ctx], first half
        hOut[b * H + hi] = hn;
        cOut[b * H + hi] = cn;
    }
}

// ============ k_scores: one wave per (b,s) dot(q_b, enc_sb) ============
__global__ void k_scores(const float* __restrict__ q, const float* __restrict__ enc,
                         float* __restrict__ sc) {
    int w = (blockIdx.x * 256 + threadIdx.x) >> 6;   // 0..32767
    int lane = threadIdx.x & 63;
    int b = w >> 10, s = w & 1023;
    const float4* e4 = (const float4*)(enc + ((long long)(s * 32 + b)) * H);
    const float4* q4 = (const float4*)(q + b * H);
    float4 a0 = e4[lane * 2], a1 = e4[lane * 2 + 1];
    float4 b0 = q4[lane * 2], b1 = q4[lane * 2 + 1];
    float v = a0.x * b0.x + a0.y * b0.y + a0.z * b0.z + a0.w * b0.w
            + a1.x * b1.x + a1.y * b1.y + a1.z * b1.z + a1.w * b1.w;
    #pragma unroll
    for (int off = 32; off > 0; off >>= 1) v += __shfl_xor(v, off);
    if (lane == 0) sc[b * S + s] = v;
}

// ============ k_softmax: block per b over S=1024 ============
__global__ void k_softmax(const float* __restrict__ sc, float* __restrict__ attn) {
    __shared__ float red[8];
    int b = blockIdx.x, t = threadIdx.x;
    float v[4];
    float m = -1e30f;
    #pragma unroll
    for (int i = 0; i < 4; ++i) {
        v[i] = sc[b * S + i * 256 + t];
        m = fmaxf(m, v[i]);
    }
    #pragma unroll
    for (int off = 32; off > 0; off >>= 1) m = fmaxf(m, __shfl_xor(m, off));
    if ((t & 63) == 0) red[t >> 6] = m;
    __syncthreads();
    m = fmaxf(fmaxf(red[0], red[1]), fmaxf(red[2], red[3]));
    float e[4], l = 0.f;
    #pragma unroll
    for (int i = 0; i < 4; ++i) { e[i] = expf(v[i] - m); l += e[i]; }
    #pragma unroll
    for (int off = 32; off > 0; off >>= 1) l += __shfl_xor(l, off);
    if ((t & 63) == 0) red[4 + (t >> 6)] = l;
    __syncthreads();
    l = red[4] + red[5] + red[6] + red[7];
    float inv = 1.f / l;
    #pragma unroll
    for (int i = 0; i < 4; ++i) attn[b * S + i * 256 + t] = e[i] * inv;
}

// ============ k_ctxp: partial context over s-chunks ============
__global__ void k_ctxp(const float* __restrict__ attn, const float* __restrict__ enc,
                       float* __restrict__ par) {
    int b = blockIdx.x >> 5, ch = blockIdx.x & 31;
    int t = threadIdx.x;
    float a0 = 0.f, a1 = 0.f;
    for (int si = 0; si < 32; ++si) {
        int s = ch * 32 + si;
        float a = attn[b * S + s];
        const float* eb = enc + ((long long)(s * 32 + b)) * H;
        a0 += a * eb[t];
        a1 += a * eb[256 + t];
    }
    float* p = par + (long long)(ch * 32 + b) * H;
    p[t] = a0;
    p[256 + t] = a1;
}

// ============ k_ctxr: reduce 32 chunks -> context ============
__global__ void k_ctxr(const float* __restrict__ par, float* __restrict__ ctxOut,
                       float* __restrict__ yT) {
    int idx = blockIdx.x * 256 + threadIdx.x;    // 0..16383
    int b = idx >> 9, h = idx & (H - 1);
    float s = 0.f;
    #pragma unroll 4
    for (int c = 0; c < 32; ++c) s += par[c * 16384 + b * H + h];
    ctxOut[b * H + h] = s;
    yT[(H + h) * 32 + b] = s;                    // y second half
}

// ============ k_gemm: logits[b][v] = y_b . Wout_v + bout_v ============
// 64 v-rows per block; 256 thr = 8 kg x 4 bg x 8 vg; thread tile 8v x 8b.
// launch_bounds(256,2): 256-VGPR cap so acc[8][8] stays in registers.
// (round 1: (256,3) drove an 84-VGPR budget -> acc spilled to scratch,
//  1.8 GB scratch WRITE_SIZE, 1060 us. Spill-free needs ~115 live VGPRs.)
#define RED_WRITE(reg) { float* rr = WT + (reg) * 2112;                       \
    _Pragma("unroll") for (int d = 0; d < 8; ++d) { int vl = vg + 8 * d;      \
    _Pragma("unroll") for (int e = 0; e < 8; ++e)                             \
        rr[vl * 33 + bg * 8 + e] = acc[d][e]; } }
#define RED_ADD(reg) { float* rr = WT + (reg) * 2112;                         \
    _Pragma("unroll") for (int d = 0; d < 8; ++d) { int vl = vg + 8 * d;      \
    _Pragma("unroll") for (int e = 0; e < 8; ++e)                             \
        acc[d][e] += rr[vl * 33 + bg * 8 + e]; } }

__global__ __launch_bounds__(256, 2)
void k_gemm(const float* __restrict__ Wout, const float* __restrict__ yTg,
            const float* __restrict__ bout, float* __restrict__ out) {
    __shared__ float WT[64 * 132];   // W tile [64 v][128 k], pad 132
    __shared__ float YS[128 * 32];   // yT tile [128 k][32 b]
    int tid = threadIdx.x;
    int v0 = blockIdx.x * 64;
    int kg = tid >> 5;
    int bg = (tid >> 3) & 3;
    int vg = tid & 7;
    float acc[8][8];
    #pragma unroll
    for (int d = 0; d < 8; ++d)
        #pragma unroll
        for (int e = 0; e < 8; ++e) acc[d][e] = 0.f;

    for (int kc = 0; kc < 1024; kc += 128) {
        // stage W tile (coalesced float4 rows), guard v >= V with zeros
        #pragma unroll
        for (int i = 0; i < 8; ++i) {
            int f = tid + i * 256;
            int v = f >> 5, j = f & 31;
            int gv = v0 + v;
            float4 w4 = make_float4(0.f, 0.f, 0.f, 0.f);
            if (gv < V) w4 = *(const float4*)(Wout + (long long)gv * 1024 + kc + j * 4);
            *(float4*)(WT + v * 132 + j * 4) = w4;
        }
        // stage y tile (contiguous)
        #pragma unroll
        for (int i = 0; i < 4; ++i) {
            int f = tid + i * 256;
            float4 y4 = *(const float4*)(yTg + kc * 32 + f * 4);
            *(float4*)(YS + f * 4) = y4;
        }
        __syncthreads();
        // compute: this thread's k range = [kg*16, kg*16+16) of chunk, in 4-groups
        #pragma unroll
        for (int g = 0; g < 4; ++g) {
            int k0 = kg * 16 + g * 4;
            float4 ya[4], yb[4];
            #pragma unroll
            for (int kk = 0; kk < 4; ++kk) {
                ya[kk] = *(const float4*)(YS + (k0 + kk) * 32 + bg * 8);
                yb[kk] = *(const float4*)(YS + (k0 + kk) * 32 + bg * 8 + 4);
            }
            #pragma unroll
            for (int d = 0; d < 8; ++d) {
                float4 w4 = *(const float4*)(WT + (vg + 8 * d) * 132 + k0);
                acc[d][0] += w4.x * ya[0].x + w4.y * ya[1].x + w4.z * ya[2].x + w4.w * ya[3].x;
                acc[d][1] += w4.x * ya[0].y + w4.y * ya[1].y + w4.z * ya[2].y + w4.w * ya[3].y;
                acc[d][2] += w4.x * ya[0].z + w4.y * ya[1].z + w4.z * ya[2].z + w4.w * ya[3].z;
                acc[d][3] += w4.x * ya[0].w + w4.y * ya[1].w + w4.z * ya[2].w + w4.w * ya[3].w;
                acc[d][4] += w4.x * yb[0].x + w4.y * yb[1].x + w4.z * yb[2].x + w4.w * yb[3].x;
                acc[d][5] += w4.x * yb[0].y + w4.y * yb[1].y + w4.z * yb[2].y + w4.w * yb[3].y;
                acc[d][6] += w4.x * yb[0].z + w4.y * yb[1].z + w4.z * yb[2].z + w4.w * yb[3].z;
                acc[d][7] += w4.x * yb[0].w + w4.y * yb[1].w + w4.z * yb[2].w + w4.w * yb[3].w;
            }
        }
        __syncthreads();
    }

    // tree-reduce the 8 kg partials in LDS (WT reused; region stride 2112)
    if (kg >= 4) RED_WRITE(kg - 4);
    __syncthreads();
    if (kg < 4) RED_ADD(kg);
    __syncthreads();
    if (kg >= 2 && kg < 4) RED_WRITE(kg - 2);
    __syncthreads();
    if (kg < 2) RED_ADD(kg);
    __syncthreads();
    if (kg == 1) RED_WRITE(0);
    __syncthreads();
    if (kg == 0) {
        RED_ADD(0);
        #pragma unroll
        for (int d = 0; d < 8; ++d) {
            int gv = v0 + vg + 8 * d;
            if (gv < V) {
                float bo = bout[gv];
                #pragma unroll
                for (int e = 0; e < 8; ++e)
                    out[(long long)(bg * 8 + e) * V + gv] = acc[d][e] + bo;
            }
        }
    }
}

// ============ k_lsep: per (b, chunk) online max/sumexp over logits ============
__global__ void k_lsep(const float* __restrict__ out, float* __restrict__ lsep) {
    __shared__ float rm[4], rl[4];
    int b = blockIdx.x >> 4, ch = blockIdx.x & 15;
    int t = threadIdx.x;
    int start = ch * 3125, end = start + 3125;
    float m = -1e30f, l = 0.f;
    for (int v = start + t; v < end; v += 256) {
        float x = out[(long long)b * V + v];
        float nm = fmaxf(m, x);
        l = l * expf(m - nm) + expf(x - nm);
        m = nm;
    }
    #pragma unroll
    for (int off = 32; off > 0; off >>= 1) {
        float m2 = __shfl_xor(m, off);
        float l2 = __shfl_xor(l, off);
        float nm = fmaxf(m, m2);
        l = l * expf(m - nm) + l2 * expf(m2 - nm);
        m = nm;
    }
    if ((t & 63) == 0) { rm[t >> 6] = m; rl[t >> 6] = l; }
    __syncthreads();
    if (t == 0) {
        m = rm[0]; l = rl[0];
        for (int i = 1; i < 4; ++i) {
            float nm = fmaxf(m, rm[i]);
            l = l * expf(m - nm) + rl[i] * expf(rm[i] - nm);
            m = nm;
        }
        lsep[(b * 16 + ch) * 2] = m;
        lsep[(b * 16 + ch) * 2 + 1] = l;
    }
}

// ============ k_final: merge lse chunks, out = logits - lse[b] (in place) ====
__global__ void k_final(const float* __restrict__ lsep, float* __restrict__ out) {
    __shared__ float lse[32];
    int t = threadIdx.x;
    if (t < 32) {
        float m = lsep[t * 32], l = lsep[t * 32 + 1];
        for (int i = 1; i < 16; ++i) {
            float m2 = lsep[t * 32 + i * 2], l2 = lsep[t * 32 + i * 2 + 1];
            float nm = fmaxf(m, m2);
            l = l * expf(m - nm) + l2 * expf(m2 - nm);
            m = nm;
        }
        lse[t] = m + logf(l);
    }
    __syncthreads();
    int idx0 = blockIdx.x * 2048 + t;
    #pragma unroll
    for (int i = 0; i < 8; ++i) {
        int idx = idx0 + i * 256;
        if (idx < B * V) {
            int b = idx / V;
            out[idx] -= lse[b];
        }
    }
}

extern "C" void kernel_launch(void* const* d_in, const int* in_sizes, int n_in,
                              void* d_out, int out_size, void* d_ws, size_t ws_size,
                              hipStream_t stream) {
    const int*   wi   = (const int*)d_in[0];
    const float* lc   = (const float*)d_in[1];
    const float* h0   = (const float*)d_in[2];
    const float* c0   = (const float*)d_in[3];
    const float* enc  = (const float*)d_in[4];
    const float* emb  = (const float*)d_in[5];
    const float* Wih  = (const float*)d_in[6];
    const float* Whh  = (const float*)d_in[7];
    const float* bih  = (const float*)d_in[8];
    const float* bhh  = (const float*)d_in[9];
    const float* Wa   = (const float*)d_in[10];
    // d_in[11] = b_a: provably cancels in softmax -> unused
    const float* Wout = (const float*)d_in[12];
    const float* bout = (const float*)d_in[13];
    float* out = (float*)d_out;
    float* ws  = (float*)d_ws;

    float* zT   = ws + ZT_OFF;
    float* gT   = ws + GT_OFF;
    float* cT   = ws + CT_OFF;
    float* q    = ws + Q_OFF;
    float* yT   = ws + YT_OFF;
    float* sc   = ws + SC_OFF;
    float* par  = ws + PAR_OFF;
    float* lsep = ws + LSEP_OFF;

    k_prep<<<256, 256, 0, stream>>>(wi, lc, h0, emb, Wa, zT, q);
    k_gates<<<2048, 256, 0, stream>>>(zT, Wih, Whh, bih, bhh, gT);
    k_point<<<64, 256, 0, stream>>>(gT, c0, 0, zT, cT, yT, out + DO_H, out + DO_C);
    k_gates<<<2048, 256, 0, stream>>>(zT, Wih, Whh, bih, bhh, gT);
    k_point<<<64, 256, 0, stream>>>(gT, cT, 1, zT, cT, yT, out + DO_H, out + DO_C);
    k_scores<<<8192, 256, 0, stream>>>(q, enc, sc);
    k_softmax<<<32, 256, 0, stream>>>(sc, out + DO_ATTN);
    k_ctxp<<<1024, 256, 0, stream>>>(out + DO_ATTN, enc, par);
    k_ctxr<<<64, 256, 0, stream>>>(par, out + DO_CTX, yT);
    k_gemm<<<(V + 63) / 64, 256, 0, stream>>>(Wout, yT, bout, out + DO_OUT);
    k_lsep<<<512, 256, 0, stream>>>(out + DO_OUT, lsep);
    k_final<<<782, 256, 0, stream>>>(lsep, out + DO_OUT);
}